// Round 8
// baseline (165.863 us; speedup 1.0000x reference)
//
#include <hip/hip_runtime.h>
#include <hip/hip_bf16.h>
#include <hip/hip_fp16.h>
#include <cstddef>
#include <cstdint>

#define BIGV 10000000.0f
#define WPV  1.0f

#define BATCH 8
#define T1N 256
#define T2N 1024
#define CN 128
#define DN 1279          // T1+T2-1

#define NTILES 640       // 20 row-groups x 8 batches x 4 col-tiles
#define FLAG_MAGIC 0x600D0000
#define TMAGIC     0x70000000   // per-tile flag value = TMAGIC + t

typedef __attribute__((ext_vector_type(2))) _Float16 half2v;

__device__ __forceinline__ float min3f(float a, float b, float c) {
    float d;
    asm("v_min3_f32 %0, %1, %2, %3" : "=v"(d) : "v"(a), "v"(b), "v"(c));
    return d;
}

// ---------------------------------------------------------------------------
// R25: fused, FULL-WIDTH cost grid.
// R22 failed (107us) because cost was throttled to 256 blocks = 1/CU: cost
// tiles are latency-bound (~35us/pass), so 2.5 serial passes = 105us. The
// proven-fast cost config is 640 one-tile blocks at ~2.5/CU (28us). R25:
// 648 blocks = 8 dp (blockIdx 0-7, resident from t=0, spin on tile flags)
// + 640 cost (one tile each, row-group-major so ascending-d groups finish
// first). dp = R22's verbatim register-double-buffer consumer (passed).
// Cost never waits -> no deadlock; worst case degenerates to serial.
// dp-variant history: ring 58.2 / reg-interleaved 50.4 / reg-grouped 55.4 /
// LDS-ring DMA 56.2 -> dp step cost is structure-invariant (~90cy/step);
// stop optimizing dp, overlap cost under it instead.
// ---------------------------------------------------------------------------
__global__ __launch_bounds__(256, 1) void fused_kernel(const float* __restrict__ A,
                                                       const float* __restrict__ Bf,
                                                       const int* __restrict__ lenA,
                                                       const int* __restrict__ lenB,
                                                       float* __restrict__ sk,
                                                       int* __restrict__ tflags,
                                                       float* __restrict__ partials,
                                                       int* __restrict__ bflags,
                                                       float* __restrict__ out) {
    __shared__ char As[64 * 256];     // 64 rows x 128 f16 ch  (16,384 B)
    __shared__ char Bs[127 * 256];    // 127 rows x 128 f16 ch (32,512 B)

    const int blk = blockIdx.x;
    const int tid = threadIdx.x;

    if (blk < BATCH) {
        // ================= dp path: one wave per batch (R22 verbatim) ======
        if (tid >= 64) return;        // waves 1-3 exit; no __syncthreads here
        const int b = blk;
        const int L = tid;            // columns 4L..4L+3

        const int la = __builtin_amdgcn_readfirstlane(lenA[b]);
        const int lb = __builtin_amdgcn_readfirstlane(lenB[b]);
        const int dEnd = la + lb - 2;     // in [638, 1278]
        const int kLast = dEnd >> 4;

        const char* lanep = (const char*)(sk + (size_t)b * DN * T1N) + (L << 4);

        float v1_0 = BIGV, v1_1 = BIGV, v1_2 = BIGV, v1_3 = BIGV;
        float v2_0 = BIGV, v2_1 = BIGV, v2_2 = BIGV, v2_3 = BIGV;
        float p1_prev = (L == 0) ? 0.0f : BIGV;   // pcp0 boundary column

        float4 A0, A1, A2, A3, A4, A5, A6, A7, A8, A9, A10, A11, A12, A13, A14, A15;
        float4 B0, B1, B2, B3, B4, B5, B6, B7, B8, B9, B10, B11, B12, B13, B14, B15;

        int g_done = -1;              // highest row-group known ready

#define WAIT_GRPS(G) do {                                                   \
        int gt_ = (G); gt_ = gt_ > 19 ? 19 : gt_;                           \
        while (g_done < gt_) {                                              \
            int gg = g_done + 1;                                            \
            for (int x_ = 0; x_ < 4; ++x_) {                                \
                int tt = (gg << 5) + (b << 2) + x_;                         \
                while (__hip_atomic_load(&tflags[tt], __ATOMIC_ACQUIRE,     \
                                         __HIP_MEMORY_SCOPE_AGENT)          \
                       != TMAGIC + tt)                                      \
                    __builtin_amdgcn_s_sleep(2);                            \
            }                                                               \
            g_done = gg;                                                    \
        }                                                                   \
    } while (0)

#define SHFL_UP1(SRC)                                                       \
    __int_as_float(__builtin_amdgcn_update_dpp(                             \
        __float_as_int(BIGV), __float_as_int(SRC),                          \
        0x138 /* wave_shr:1 */, 0xF, 0xF, false))

#define LOAD1(DST, KB, R) do {                                              \
        int row_ = ((KB) << 4) + (R);                                       \
        row_ = row_ > dEnd ? dEnd : row_;                                   \
        DST = *(const float4*)(lanep + (size_t)row_ * (T1N * 4));           \
    } while (0)

#define LOADALL(P, KB) do {                                                 \
        LOAD1(P##0, KB, 0);   LOAD1(P##1, KB, 1);   LOAD1(P##2, KB, 2);     \
        LOAD1(P##3, KB, 3);   LOAD1(P##4, KB, 4);   LOAD1(P##5, KB, 5);     \
        LOAD1(P##6, KB, 6);   LOAD1(P##7, KB, 7);   LOAD1(P##8, KB, 8);     \
        LOAD1(P##9, KB, 9);   LOAD1(P##10, KB, 10); LOAD1(P##11, KB, 11);   \
        LOAD1(P##12, KB, 12); LOAD1(P##13, KB, 13); LOAD1(P##14, KB, 14);   \
        LOAD1(P##15, KB, 15);                                               \
    } while (0)

#define DP_STEP(C4) do {                                                    \
        float4 c = (C4);                                                    \
        float p1 = SHFL_UP1(v1_3);                                          \
        float w0 = v1_0 + WPV, w1 = v1_1 + WPV;                             \
        float w2 = v1_2 + WPV, w3 = v1_3 + WPV;                             \
        float wp = p1 + WPV;                                                \
        float n0 = c.x + min3f(p1_prev, w0, wp);                            \
        float n1 = c.y + min3f(v2_0, w1, w0);                               \
        float n2 = c.z + min3f(v2_1, w2, w1);                               \
        float n3 = c.w + min3f(v2_2, w3, w2);                               \
        p1_prev = p1;                                                       \
        v2_0 = v1_0; v2_1 = v1_1; v2_2 = v1_2; v2_3 = v1_3;                 \
        v1_0 = n0;   v1_1 = n1;   v1_2 = n2;   v1_3 = n3;                   \
    } while (0)

#define DP_STEP_G(C4, R) do {                                               \
        float4 c = (C4);                                                    \
        float p1 = SHFL_UP1(v1_3);                                          \
        float w0 = v1_0 + WPV, w1 = v1_1 + WPV;                             \
        float w2 = v1_2 + WPV, w3 = v1_3 + WPV;                             \
        float wp = p1 + WPV;                                                \
        float n0 = c.x + min3f(p1_prev, w0, wp);                            \
        float n1 = c.y + min3f(v2_0, w1, w0);                               \
        float n2 = c.z + min3f(v2_1, w2, w1);                               \
        float n3 = c.w + min3f(v2_2, w3, w2);                               \
        if ((R) <= rem) {                                                   \
            p1_prev = p1;                                                   \
            v2_0 = v1_0; v2_1 = v1_1; v2_2 = v1_2; v2_3 = v1_3;             \
            v1_0 = n0;   v1_1 = n1;   v1_2 = n2;   v1_3 = n3;               \
        }                                                                   \
    } while (0)

#define STEP_RL(C4, KB, R) do { DP_STEP(C4); LOAD1(C4, KB, R); } while (0)

#define PROC_RELOAD(P, KB) do {                                             \
        STEP_RL(P##0, KB, 0);   STEP_RL(P##1, KB, 1);                       \
        STEP_RL(P##2, KB, 2);   STEP_RL(P##3, KB, 3);                       \
        STEP_RL(P##4, KB, 4);   STEP_RL(P##5, KB, 5);                       \
        STEP_RL(P##6, KB, 6);   STEP_RL(P##7, KB, 7);                       \
        STEP_RL(P##8, KB, 8);   STEP_RL(P##9, KB, 9);                       \
        STEP_RL(P##10, KB, 10); STEP_RL(P##11, KB, 11);                     \
        STEP_RL(P##12, KB, 12); STEP_RL(P##13, KB, 13);                     \
        STEP_RL(P##14, KB, 14); STEP_RL(P##15, KB, 15);                     \
    } while (0)

#define PROC_FULL(P) do {                                                   \
        DP_STEP(P##0);  DP_STEP(P##1);  DP_STEP(P##2);  DP_STEP(P##3);      \
        DP_STEP(P##4);  DP_STEP(P##5);  DP_STEP(P##6);  DP_STEP(P##7);      \
        DP_STEP(P##8);  DP_STEP(P##9);  DP_STEP(P##10); DP_STEP(P##11);     \
        DP_STEP(P##12); DP_STEP(P##13); DP_STEP(P##14); DP_STEP(P##15);     \
    } while (0)

#define PROC_GUARD(P) do {                                                  \
        DP_STEP_G(P##0, 0);   DP_STEP_G(P##1, 1);   DP_STEP_G(P##2, 2);     \
        DP_STEP_G(P##3, 3);   DP_STEP_G(P##4, 4);   DP_STEP_G(P##5, 5);     \
        DP_STEP_G(P##6, 6);   DP_STEP_G(P##7, 7);   DP_STEP_G(P##8, 8);     \
        DP_STEP_G(P##9, 9);   DP_STEP_G(P##10, 10); DP_STEP_G(P##11, 11);   \
        DP_STEP_G(P##12, 12); DP_STEP_G(P##13, 13); DP_STEP_G(P##14, 14);   \
        DP_STEP_G(P##15, 15);                                               \
    } while (0)

        // prologue: blocks 0 and 1 (rows 0..31, group 0)
        WAIT_GRPS(0);
        LOADALL(A, 0);
        LOADALL(B, 1);

        int k = 0;
        while (k + 1 < kLast) {           // blocks k, k+1 full; prefetch k+2,k+3
            WAIT_GRPS((k + 3) >> 2);      // cover all rows touched by prefetch
            PROC_RELOAD(A, k + 2);
            PROC_RELOAD(B, k + 3);
            k += 2;
        }
        if (k < kLast) {                  // k == kLast-1: full A, guarded B
            PROC_FULL(A);
            const int rem = dEnd & 15;
            PROC_GUARD(B);
        } else {                          // k == kLast: guarded A
            const int rem = dEnd & 15;
            PROC_GUARD(A);
        }

        // publish partials[b] with replay-safe magic flag
        const int tcap = la - 1;
        if (L == (tcap >> 2)) {
            const int kk = tcap & 3;
            float r = v1_0;
            if (kk == 1) r = v1_1;
            else if (kk == 2) r = v1_2;
            else if (kk == 3) r = v1_3;
            partials[b] = r;
            __threadfence();
            __hip_atomic_store(&bflags[b], FLAG_MAGIC + b,
                               __ATOMIC_RELEASE, __HIP_MEMORY_SCOPE_AGENT);
        }

        // block 0: gather all 8 partials and write the final sum
        if (b == 0 && L == 0) {
            float s = 0.0f;
            for (int i = 0; i < BATCH; ++i) {
                while (__hip_atomic_load(&bflags[i], __ATOMIC_ACQUIRE,
                                         __HIP_MEMORY_SCOPE_AGENT) != FLAG_MAGIC + i)
                    __builtin_amdgcn_s_sleep(2);
                s += __hip_atomic_load(&partials[i], __ATOMIC_RELAXED,
                                       __HIP_MEMORY_SCOPE_AGENT);
            }
            out[0] = s;
        }
        return;
#undef PROC_GUARD
#undef PROC_FULL
#undef PROC_RELOAD
#undef STEP_RL
#undef DP_STEP_G
#undef DP_STEP
#undef LOADALL
#undef LOAD1
#undef SHFL_UP1
#undef WAIT_GRPS
    }

    // ================= cost path: ONE tile per block (640 blocks) ==========
    const int t  = blk - BATCH;           // 0..639, row-group-major
    const int q  = t >> 5;                // row-group 0..19
    const int rr = t & 31;
    const int tb = rr >> 2;               // batch
    const int tx = rr & 3;                // col-tile
    const int d0 = q << 6;
    const int j0 = tx << 6;

    const int dEnd = lenA[tb] + lenB[tb] - 2;

    if (d0 <= dEnd) {                     // uniform per block
        const float* Ab = A  + (size_t)tb * T1N * CN;
        const float* Bb = Bf + (size_t)tb * T2N * CN;

        const int tj = tid & 15;
        const int td = tid >> 4;
        const int brow0 = td - tj + 63;   // rows brow0+16(m-3) in [0,126]
        const int rbase = d0 - j0 - 63;

        // swizzled byte offset: row stride 256B; 16B groups rotated by row
#define SWB(row, g) (((row) << 8) + ((((g) + (row)) & 15) << 4))

        // ---- stage A: 64 rows x 32 f32-quads = 2048 -> 8 per thread ----
        #pragma unroll
        for (int i = 0; i < 8; ++i) {
            int idx = tid + i * 256;
            int row = idx >> 5;
            int qq  = idx & 31;           // channels 4q..4q+3
            float4 f = *(const float4*)(Ab + (size_t)(j0 + row) * CN + (qq << 2));
            half2v h0 = { (_Float16)f.x, (_Float16)f.y };
            half2v h1 = { (_Float16)f.z, (_Float16)f.w };
            char* dst = As + SWB(row, qq >> 1) + ((qq & 1) << 3);
            ((uint32_t*)dst)[0] = __builtin_bit_cast(uint32_t, h0);
            ((uint32_t*)dst)[1] = __builtin_bit_cast(uint32_t, h1);
        }
        // ---- stage B: 127 rows x 32 quads = 4064 -> 16 per thread ----
        #pragma unroll
        for (int i = 0; i < 16; ++i) {
            int idx = tid + i * 256;
            if (idx < 4064) {
                int row = idx >> 5;
                int qq  = idx & 31;
                int gr = rbase + row;
                gr = gr < 0 ? 0 : (gr > T2N - 1 ? T2N - 1 : gr);
                float4 f = *(const float4*)(Bb + (size_t)gr * CN + (qq << 2));
                half2v h0 = { (_Float16)f.x, (_Float16)f.y };
                half2v h1 = { (_Float16)f.z, (_Float16)f.w };
                char* dst = Bs + SWB(row, qq >> 1) + ((qq & 1) << 3);
                ((uint32_t*)dst)[0] = __builtin_bit_cast(uint32_t, h0);
                ((uint32_t*)dst)[1] = __builtin_bit_cast(uint32_t, h1);
            }
        }
        __syncthreads();

        float acc[4][4];
        #pragma unroll
        for (int i = 0; i < 4; ++i)
            #pragma unroll
            for (int j = 0; j < 4; ++j) acc[i][j] = 0.0f;

        const half2v one2 = { (_Float16)1.0f, (_Float16)1.0f };

        for (int g = 0; g < 16; ++g) {        // 8 channels per group
            uint4 a4[4], bv[7];
            #pragma unroll
            for (int ji = 0; ji < 4; ++ji) {
                int row = tj + 16 * ji;
                a4[ji] = *(const uint4*)(As + SWB(row, g));
            }
            #pragma unroll
            for (int m = 0; m < 7; ++m) {
                int row = brow0 + 16 * (m - 3);
                bv[m] = *(const uint4*)(Bs + SWB(row, g));
            }
            #pragma unroll
            for (int dk = 0; dk < 4; ++dk) {
                #pragma unroll
                for (int ji = 0; ji < 4; ++ji) {
                    uint4 au = a4[ji];
                    uint4 bu = bv[dk - ji + 3];
                    float a = acc[dk][ji];
                    #pragma unroll
                    for (int w = 0; w < 4; ++w) {
                        uint32_t ua = (&au.x)[w];
                        uint32_t ub = (&bu.x)[w];
                        half2v d2 = __builtin_bit_cast(half2v, ua)
                                  - __builtin_bit_cast(half2v, ub);
                        uint32_t du = __builtin_bit_cast(uint32_t, d2) & 0x7FFF7FFFu;
#if __has_builtin(__builtin_amdgcn_fdot2)
                        a = __builtin_amdgcn_fdot2(__builtin_bit_cast(half2v, du),
                                                   one2, a, false);
#else
                        half2v ad = __builtin_bit_cast(half2v, du);
                        a += (float)ad.x + (float)ad.y;
#endif
                    }
                    acc[dk][ji] = a;
                }
            }
        }
#undef SWB

        #pragma unroll
        for (int dk = 0; dk < 4; ++dk) {
            int d = d0 + td + 16 * dk;
            if (d < DN) {
                size_t rowoff = ((size_t)tb * DN + d) * T1N;
                #pragma unroll
                for (int ji = 0; ji < 4; ++ji) {
                    int j = j0 + tj + 16 * ji;
                    sk[rowoff + j] = acc[dk][ji] * (1.0f / 128.0f);
                }
            }
        }
    }

    __syncthreads();                      // all sk stores issued
    if (tid == 0) {
        __threadfence();                  // make sk stores agent-visible
        __hip_atomic_store(&tflags[t], TMAGIC + t,
                           __ATOMIC_RELEASE, __HIP_MEMORY_SCOPE_AGENT);
    }
}

extern "C" void kernel_launch(void* const* d_in, const int* in_sizes, int n_in,
                              void* d_out, int out_size, void* d_ws, size_t ws_size,
                              hipStream_t stream) {
    const float* feaA = (const float*)d_in[0];
    const int*   lenA = (const int*)d_in[1];
    const float* feaB = (const float*)d_in[2];
    const int*   lenB = (const int*)d_in[3];

    float* sk       = (float*)d_ws;                       // 8*1279*256*4 B
    float* partials = (float*)((char*)d_ws + (size_t)BATCH * DN * T1N * sizeof(float));
    int*   bflags   = (int*)(partials + BATCH);
    int*   tflags   = bflags + BATCH;                     // 640 ints

    fused_kernel<<<BATCH + NTILES, 256, 0, stream>>>(feaA, feaB, lenA, lenB,
                                                     sk, tflags, partials, bflags,
                                                     (float*)d_out);
}

// Round 9
// 142.991 us; speedup vs baseline: 1.1600x; 1.1600x over previous
//
#include <hip/hip_runtime.h>
#include <hip/hip_bf16.h>
#include <hip/hip_fp16.h>
#include <cstddef>
#include <cstdint>

#define BIGV 10000000.0f
#define WPV  1.0f

#define BATCH 8
#define T1N 256
#define T2N 1024
#define CN 128
#define DN 1279          // T1+T2-1

#define FLAG_MAGIC 0x600D0000

typedef __attribute__((ext_vector_type(2))) _Float16 half2v;

// ---------------------------------------------------------------------------
// Kernel 1 (R19, unchanged): cost with F16 LDS staging + packed math.
// ---------------------------------------------------------------------------
__global__ __launch_bounds__(256) void cost_kernel(const float* __restrict__ A,
                                                   const float* __restrict__ Bf,
                                                   const int* __restrict__ lenA,
                                                   const int* __restrict__ lenB,
                                                   float* __restrict__ sk) {
    __shared__ char As[64 * 256];     // 64 rows x 128 f16 ch  (16,384 B)
    __shared__ char Bs[127 * 256];    // 127 rows x 128 f16 ch (32,512 B)

    const int b  = blockIdx.z;
    const int d0 = blockIdx.y * 64;
    const int j0 = blockIdx.x * 64;
    const int tid = threadIdx.x;

    const int dEnd = lenA[b] + lenB[b] - 2;
    if (d0 > dEnd) return;            // rows never consumed

    const float* Ab = A  + (size_t)b * T1N * CN;
    const float* Bb = Bf + (size_t)b * T2N * CN;

    const int tj = tid & 15;
    const int td = tid >> 4;
    const int brow0 = td - tj + 63;   // rows brow0+16(m-3) in [0,126]
    const int rbase = d0 - j0 - 63;

    // swizzled byte offset: row stride 256B; 16B groups rotated by row
#define SWB(row, g) (((row) << 8) + ((((g) + (row)) & 15) << 4))

    // ---- stage A: 64 rows x 32 f32-quads = 2048 -> 8 per thread ----
    #pragma unroll
    for (int i = 0; i < 8; ++i) {
        int idx = tid + i * 256;
        int row = idx >> 5;
        int q   = idx & 31;               // channels 4q..4q+3
        float4 f = *(const float4*)(Ab + (size_t)(j0 + row) * CN + (q << 2));
        half2v h0 = { (_Float16)f.x, (_Float16)f.y };
        half2v h1 = { (_Float16)f.z, (_Float16)f.w };
        char* dst = As + SWB(row, q >> 1) + ((q & 1) << 3);
        ((uint32_t*)dst)[0] = __builtin_bit_cast(uint32_t, h0);
        ((uint32_t*)dst)[1] = __builtin_bit_cast(uint32_t, h1);
    }
    // ---- stage B: 127 rows x 32 quads = 4064 -> 16 per thread (guarded) ----
    #pragma unroll
    for (int i = 0; i < 16; ++i) {
        int idx = tid + i * 256;
        if (idx < 4064) {
            int row = idx >> 5;
            int q   = idx & 31;
            int gr = rbase + row;
            gr = gr < 0 ? 0 : (gr > T2N - 1 ? T2N - 1 : gr);
            float4 f = *(const float4*)(Bb + (size_t)gr * CN + (q << 2));
            half2v h0 = { (_Float16)f.x, (_Float16)f.y };
            half2v h1 = { (_Float16)f.z, (_Float16)f.w };
            char* dst = Bs + SWB(row, q >> 1) + ((q & 1) << 3);
            ((uint32_t*)dst)[0] = __builtin_bit_cast(uint32_t, h0);
            ((uint32_t*)dst)[1] = __builtin_bit_cast(uint32_t, h1);
        }
    }
    __syncthreads();

    float acc[4][4];
    #pragma unroll
    for (int i = 0; i < 4; ++i)
        #pragma unroll
        for (int j = 0; j < 4; ++j) acc[i][j] = 0.0f;

    const half2v one2 = { (_Float16)1.0f, (_Float16)1.0f };

    for (int g = 0; g < 16; ++g) {        // 8 channels per group
        uint4 a4[4], bv[7];
        #pragma unroll
        for (int ji = 0; ji < 4; ++ji) {
            int row = tj + 16 * ji;
            a4[ji] = *(const uint4*)(As + SWB(row, g));
        }
        #pragma unroll
        for (int m = 0; m < 7; ++m) {
            int row = brow0 + 16 * (m - 3);
            bv[m] = *(const uint4*)(Bs + SWB(row, g));
        }
        #pragma unroll
        for (int dk = 0; dk < 4; ++dk) {
            #pragma unroll
            for (int ji = 0; ji < 4; ++ji) {
                uint4 au = a4[ji];
                uint4 bu = bv[dk - ji + 3];
                float a = acc[dk][ji];
                #pragma unroll
                for (int w = 0; w < 4; ++w) {
                    uint32_t ua = (&au.x)[w];
                    uint32_t ub = (&bu.x)[w];
                    half2v d2 = __builtin_bit_cast(half2v, ua)
                              - __builtin_bit_cast(half2v, ub);
                    uint32_t du = __builtin_bit_cast(uint32_t, d2) & 0x7FFF7FFFu;
#if __has_builtin(__builtin_amdgcn_fdot2)
                    a = __builtin_amdgcn_fdot2(__builtin_bit_cast(half2v, du),
                                               one2, a, false);
#else
                    half2v ad = __builtin_bit_cast(half2v, du);
                    a += (float)ad.x + (float)ad.y;
#endif
                }
                acc[dk][ji] = a;
            }
        }
    }
#undef SWB

    #pragma unroll
    for (int dk = 0; dk < 4; ++dk) {
        int d = d0 + td + 16 * dk;
        if (d < DN) {
            size_t rowoff = ((size_t)b * DN + d) * T1N;
            #pragma unroll
            for (int ji = 0; ji < 4; ++ji) {
                int j = j0 + tj + 16 * ji;
                sk[rowoff + j] = acc[dk][ji] * (1.0f / 128.0f);
            }
        }
    }
}

// ---------------------------------------------------------------------------
// Kernel 2 (R26): dp with MIN-PLUS RECURRENCE DOUBLING (2 rows/iteration).
// Evidence: 4 memory structures all 50-58us -> memory exonerated. VALUBusy
// 0.33% chip = ~40% per-wave -> step ~70cy, ~28 issuing, ~42 stalled on the
// serial chain v1_3 -> +wp -> min3 -> +c -> v1_3 (single wave: program-order
// issue cannot skip a stalled dependent op). Doubling: min(x,y,z)+w ==
// min(x+w,y+w,z+w) exactly, so row d+1 computes from rows d-1/d-2 via
// m2[j] = (c_d[j]+wp) + q[j] (q = row d's min term) in PARALLEL with row d.
// Pair = 32 VALU, chain ~30cy vs ~140cy for 2 singles. Rows 0,1 + tail
// block stay on the proven single-step macro (R3 seeding/guard/extraction
// verbatim). Memory = R3's proven interleaved reload double-buffer.
// Predict dp 50.4 -> 30-40us.
// ---------------------------------------------------------------------------
__device__ __forceinline__ float min3f(float a, float b, float c) {
    float d;
    asm("v_min3_f32 %0, %1, %2, %3" : "=v"(d) : "v"(a), "v"(b), "v"(c));
    return d;
}

__global__ __launch_bounds__(64, 1) void dp_pair_kernel(const float* __restrict__ sk,
                                                        const int* __restrict__ lenA,
                                                        const int* __restrict__ lenB,
                                                        float* __restrict__ partials,
                                                        int* __restrict__ flags,
                                                        float* __restrict__ out) {
    const int b = blockIdx.x;
    const int L = threadIdx.x;            // 0..63, columns 4L..4L+3

    const int la = __builtin_amdgcn_readfirstlane(lenA[b]);
    const int lb = __builtin_amdgcn_readfirstlane(lenB[b]);
    const int dEnd = la + lb - 2;         // in [638, 1278]
    const int kLast = dEnd >> 4;          // in [39, 79]

    const char* lanep = (const char*)(sk + (size_t)b * DN * T1N) + (L << 4);

    // p1 = row d-1, p2 = row d-2 (invariant at every iteration boundary)
    float p1_0 = BIGV, p1_1 = BIGV, p1_2 = BIGV, p1_3 = BIGV;
    float p2_0 = BIGV, p2_1 = BIGV, p2_2 = BIGV, p2_3 = BIGV;
    float pp = (L == 0) ? 0.0f : BIGV;    // pcp0 boundary (rows 0,1 + tail only)

    float4 A0, A1, A2, A3, A4, A5, A6, A7, A8, A9, A10, A11, A12, A13, A14, A15;
    float4 B0, B1, B2, B3, B4, B5, B6, B7, B8, B9, B10, B11, B12, B13, B14, B15;

#define SHFL_UP1(SRC)                                                       \
    __int_as_float(__builtin_amdgcn_update_dpp(                             \
        __float_as_int(BIGV), __float_as_int(SRC),                          \
        0x138 /* wave_shr:1 */, 0xF, 0xF, false))

    // rows > dEnd clamp to dEnd (always a written sk row; proven in R3)
#define LOAD1(DST, KB, R) do {                                              \
        int row_ = ((KB) << 4) + (R);                                       \
        row_ = row_ > dEnd ? dEnd : row_;                                   \
        DST = *(const float4*)(lanep + (size_t)row_ * (T1N * 4));           \
    } while (0)

#define LOADALL(P, KB) do {                                                 \
        LOAD1(P##0, KB, 0);   LOAD1(P##1, KB, 1);   LOAD1(P##2, KB, 2);     \
        LOAD1(P##3, KB, 3);   LOAD1(P##4, KB, 4);   LOAD1(P##5, KB, 5);     \
        LOAD1(P##6, KB, 6);   LOAD1(P##7, KB, 7);   LOAD1(P##8, KB, 8);     \
        LOAD1(P##9, KB, 9);   LOAD1(P##10, KB, 10); LOAD1(P##11, KB, 11);   \
        LOAD1(P##12, KB, 12); LOAD1(P##13, KB, 13); LOAD1(P##14, KB, 14);   \
        LOAD1(P##15, KB, 15);                                               \
    } while (0)

    // single step (R3-proven math), rotating, maintains pp carry
#define SSTEP(C4) do {                                                      \
        float4 c_ = (C4);                                                   \
        float pone_ = SHFL_UP1(p1_3);                                       \
        float w0_ = p1_0 + WPV, w1_ = p1_1 + WPV;                           \
        float w2_ = p1_2 + WPV, w3_ = p1_3 + WPV;                           \
        float wp_ = pone_ + WPV;                                            \
        float n0_ = c_.x + min3f(pp, w0_, wp_);                             \
        float n1_ = c_.y + min3f(p2_0, w1_, w0_);                           \
        float n2_ = c_.z + min3f(p2_1, w2_, w1_);                           \
        float n3_ = c_.w + min3f(p2_2, w3_, w2_);                           \
        pp = pone_;                                                         \
        p2_0 = p1_0; p2_1 = p1_1; p2_2 = p1_2; p2_3 = p1_3;                 \
        p1_0 = n0_;  p1_1 = n1_;  p1_2 = n2_;  p1_3 = n3_;                  \
    } while (0)

    // fused pair: rows r (CA) and r+1 (CB) from (p1=r-1, p2=r-2).
    // q = row r's min term; n = c1+q -> new p2; m2 = (c1+wp)+q (exact
    // redistribution of (c1+q)+wp's min); m = c2+min3(p1[j-1],m2,m2[j-1])
    // -> new p1. Three dpp carries: p1[-1], p2[-1], m2[-1].
#define PAIR(CA, CB) do {                                                   \
        float s1_ = SHFL_UP1(p1_3);                                         \
        float t1_ = SHFL_UP1(p2_3);                                         \
        float w0_ = p1_0 + WPV, w1_ = p1_1 + WPV;                           \
        float w2_ = p1_2 + WPV, w3_ = p1_3 + WPV;                           \
        float ws_ = s1_ + WPV;                                              \
        float q0_ = min3f(t1_,  w0_, ws_);                                  \
        float q1_ = min3f(p2_0, w1_, w0_);                                  \
        float q2_ = min3f(p2_1, w2_, w1_);                                  \
        float q3_ = min3f(p2_2, w3_, w2_);                                  \
        float4 ca_ = (CA), cb_ = (CB);                                      \
        float g0_ = ca_.x + WPV, g1_ = ca_.y + WPV;                         \
        float g2_ = ca_.z + WPV, g3_ = ca_.w + WPV;                         \
        float m20_ = g0_ + q0_, m21_ = g1_ + q1_;                           \
        float m22_ = g2_ + q2_, m23_ = g3_ + q3_;                           \
        float u_ = SHFL_UP1(m23_);                                          \
        float h0_ = min3f(s1_,  m20_, u_);                                  \
        float h1_ = min3f(p1_0, m21_, m20_);                                \
        float h2_ = min3f(p1_1, m22_, m21_);                                \
        float h3_ = min3f(p1_2, m23_, m22_);                                \
        p2_0 = ca_.x + q0_; p2_1 = ca_.y + q1_;                             \
        p2_2 = ca_.z + q2_; p2_3 = ca_.w + q3_;                             \
        p1_0 = cb_.x + h0_; p1_1 = cb_.y + h1_;                             \
        p1_2 = cb_.z + h2_; p1_3 = cb_.w + h3_;                             \
    } while (0)

#define PAIR_RL(CA, CB, KB, RA, RB) do {                                    \
        PAIR(CA, CB); LOAD1(CA, KB, RA); LOAD1(CB, KB, RB);                 \
    } while (0)

#define PROC_RL(P, KB) do {                                                 \
        PAIR_RL(P##0,  P##1,  KB, 0, 1);  PAIR_RL(P##2,  P##3,  KB, 2, 3);  \
        PAIR_RL(P##4,  P##5,  KB, 4, 5);  PAIR_RL(P##6,  P##7,  KB, 6, 7);  \
        PAIR_RL(P##8,  P##9,  KB, 8, 9);  PAIR_RL(P##10, P##11, KB, 10, 11);\
        PAIR_RL(P##12, P##13, KB, 12, 13);PAIR_RL(P##14, P##15, KB, 14, 15);\
    } while (0)

#define PROC_FULL(P) do {                                                   \
        PAIR(P##0,  P##1);  PAIR(P##2,  P##3);                              \
        PAIR(P##4,  P##5);  PAIR(P##6,  P##7);                              \
        PAIR(P##8,  P##9);  PAIR(P##10, P##11);                             \
        PAIR(P##12, P##13); PAIR(P##14, P##15);                             \
    } while (0)

#define GS(C4, R) do { if ((R) <= rem) SSTEP(C4); } while (0)
#define TAIL(P) do {                                                        \
        pp = SHFL_UP1(p2_3);  /* row R-2 col[-1] */                         \
        GS(P##0, 0);   GS(P##1, 1);   GS(P##2, 2);   GS(P##3, 3);           \
        GS(P##4, 4);   GS(P##5, 5);   GS(P##6, 6);   GS(P##7, 7);           \
        GS(P##8, 8);   GS(P##9, 9);   GS(P##10, 10); GS(P##11, 11);         \
        GS(P##12, 12); GS(P##13, 13); GS(P##14, 14); GS(P##15, 15);         \
    } while (0)

    // prologue: blocks 0,1 in flight
    LOADALL(A, 0);
    LOADALL(B, 1);

    // peel block 0: rows 0,1 single (pp-seeded), rows 2..15 in pairs;
    // reload block 2 into A after each consumption
    SSTEP(A0); LOAD1(A0, 2, 0);
    SSTEP(A1); LOAD1(A1, 2, 1);
    PAIR_RL(A2,  A3,  2, 2, 3);   PAIR_RL(A4,  A5,  2, 4, 5);
    PAIR_RL(A6,  A7,  2, 6, 7);   PAIR_RL(A8,  A9,  2, 8, 9);
    PAIR_RL(A10, A11, 2, 10, 11); PAIR_RL(A12, A13, 2, 12, 13);
    PAIR_RL(A14, A15, 2, 14, 15);

    // peel block 1: 8 pairs, reload block 3 into B
    PROC_RL(B, 3);

    // main loop: A=block k, B=block k+1 (full), reload k+2 / k+3
    int k = 2;
    while (k + 1 < kLast) {
        PROC_RL(A, k + 2);
        PROC_RL(B, k + 3);
        k += 2;
    }

    const int rem = dEnd & 15;
    if (k < kLast) {                      // k == kLast-1: full A, tail B
        PROC_FULL(A);
        TAIL(B);
    } else {                              // k == kLast: tail A
        TAIL(A);
    }

    // publish partials[b] (R3-proven extraction: p1 = last committed row)
    const int tcap = la - 1;
    if (L == (tcap >> 2)) {
        const int kk = tcap & 3;
        float r = p1_0;
        if (kk == 1) r = p1_1;
        else if (kk == 2) r = p1_2;
        else if (kk == 3) r = p1_3;
        partials[b] = r;
        __threadfence();
        __hip_atomic_store(&flags[b], FLAG_MAGIC + b,
                           __ATOMIC_RELEASE, __HIP_MEMORY_SCOPE_AGENT);
    }

    // block 0: gather all 8 partials and write the final sum
    if (b == 0 && L == 0) {
        float s = 0.0f;
        for (int i = 0; i < BATCH; ++i) {
            while (__hip_atomic_load(&flags[i], __ATOMIC_ACQUIRE,
                                     __HIP_MEMORY_SCOPE_AGENT) != FLAG_MAGIC + i)
                __builtin_amdgcn_s_sleep(2);
            s += __hip_atomic_load(&partials[i], __ATOMIC_RELAXED,
                                   __HIP_MEMORY_SCOPE_AGENT);
        }
        out[0] = s;
    }
#undef TAIL
#undef GS
#undef PROC_FULL
#undef PROC_RL
#undef PAIR_RL
#undef PAIR
#undef SSTEP
#undef LOADALL
#undef LOAD1
#undef SHFL_UP1
}

extern "C" void kernel_launch(void* const* d_in, const int* in_sizes, int n_in,
                              void* d_out, int out_size, void* d_ws, size_t ws_size,
                              hipStream_t stream) {
    const float* feaA = (const float*)d_in[0];
    const int*   lenA = (const int*)d_in[1];
    const float* feaB = (const float*)d_in[2];
    const int*   lenB = (const int*)d_in[3];

    float* sk       = (float*)d_ws;                       // 8*1279*256*4 B
    float* partials = (float*)((char*)d_ws + (size_t)BATCH * DN * T1N * sizeof(float));
    int*   flags    = (int*)(partials + BATCH);

    cost_kernel<<<dim3(T1N / 64, (DN + 63) / 64, BATCH), 256, 0, stream>>>(feaA, feaB, lenA, lenB, sk);
    dp_pair_kernel<<<BATCH, 64, 0, stream>>>(sk, lenA, lenB, partials, flags, (float*)d_out);
}